// Round 8
// baseline (325.384 us; speedup 1.0000x reference)
//
#include <hip/hip_runtime.h>
#include <cmath>

// SimplifiedSSM: B=2, L=2048, d_model=768, d_state=16, d_inner=1536
// ROUND 22: scans rewritten with cooperative LDS staging (canonical §5
// pattern): per 8-step group each WAVE issues ONE global_load_lds (1KB panel
// of one stream: w0 dlt, w1 xcb, w2 zg, w3 BC), 3-deep buffer rotation,
// counted vmcnt(1) + raw s_barrier (no mid-loop full drain). Compute core
// (q-split, exp2(A2), shfl-reduce, rotated stores) unchanged from R21.
// R19's register ping-pong removed (left 750cy/group exposed: tiny scalar
// loads + shallow prefetch). GEMMs/prep/conv/xproj frozen from R21.
#define DMODEL 768
#define DINNER 1536
#define NSTATE 16
#define SEQL   2048
#define NCHUNK 32
#define CHLEN  64      // SEQL / NCHUNK

#define DT_F32  0
#define DT_BF16 1
#define DT_ZERO 2

typedef __bf16 bf16x8 __attribute__((ext_vector_type(8)));
typedef float  f32x4  __attribute__((ext_vector_type(4)));

typedef __attribute__((address_space(3))) unsigned short lds_us;
typedef const __attribute__((address_space(1))) unsigned short glob_us;

__device__ __forceinline__ void async_cp16(glob_us* g, lds_us* l) {
    __builtin_amdgcn_global_load_lds((const __attribute__((address_space(1))) void*)g,
                                     (__attribute__((address_space(3))) void*)l, 16, 0, 0);
}

__device__ __forceinline__ float bf2f(unsigned short h) {
    union { unsigned u; float f; } v; v.u = ((unsigned)h) << 16; return v.f;
}
__device__ __forceinline__ unsigned short f2bf(float f) {
    union { float f; unsigned u; } v; v.f = f;
    unsigned r = (v.u + 0x7FFFu + ((v.u >> 16) & 1u)) >> 16;
    return (unsigned short)r;
}
__device__ int detect_dtype(const void* p) {
    const unsigned* u = (const unsigned*)p;
    int nzlo = 0, band = 0, anynz = 0;
    for (int i = 0; i < 64; ++i) {
        unsigned w = u[i];
        anynz |= (w != 0);
        unsigned lo = w & 0xFFFFu;
        if (lo) {
            ++nzlo;
            unsigned e8 = (lo >> 7) & 0xFF;
            if (e8 >= 0x60 && e8 <= 0x8E) ++band;
        }
    }
    if (nzlo >= 8) return (band * 2 > nzlo) ? DT_BF16 : DT_F32;
    return anynz ? DT_F32 : DT_ZERO;
}
__device__ __forceinline__ float LD(const void* p, size_t i, int dt) {
    if (dt == DT_BF16) return bf2f(((const unsigned short*)p)[i]);
    if (dt == DT_F32)  return ((const float*)p)[i];
    return 0.f;
}

// ---- fused prep: params->f32 (A_log -> A2) | x->bf16 | 3 weight transposes ----
// blocks: [0,324) params, [324,1860) x (8 elem/thread),
//         [1860,2436) in_w, [2436,3012) dt_w, [3012,3300) out_w (64x64 tiles)
__global__ __launch_bounds__(256) void prep_kernel(
    const void* __restrict__ x, const void* __restrict__ in_w,
    const void* __restrict__ cw, const void* __restrict__ cb,
    const void* __restrict__ xp, const void* __restrict__ dt_w,
    const void* __restrict__ db, const void* __restrict__ Al,
    const void* __restrict__ Dv, const void* __restrict__ out_w,
    unsigned short* __restrict__ xb, unsigned short* __restrict__ inT,
    unsigned short* __restrict__ dtT, unsigned short* __restrict__ outT,
    float* __restrict__ pf)
{
    __shared__ unsigned short tile[64][68];
    __shared__ int dts[6];
    const int blk = blockIdx.x;
    const int t   = threadIdx.x;

    if (blk < 324) {
        if (t == 0) {
            dts[0] = detect_dtype(cw); dts[1] = detect_dtype(cb);
            dts[2] = detect_dtype(db); dts[3] = detect_dtype(Al);
            dts[4] = detect_dtype(Dv); dts[5] = detect_dtype(xp);
        }
        __syncthreads();
        int g = blk * 256 + t;
        if (g >= 82944) return;
        const void* src; int local; int which;
        if      (g <  4608) { src = cw; local = g;         which = 0; }
        else if (g <  6144) { src = cb; local = g - 4608;  which = 1; }
        else if (g <  7680) { src = db; local = g - 6144;  which = 2; }
        else if (g < 32256) { src = Al; local = g - 7680;  which = 3; }
        else if (g < 33792) { src = Dv; local = g - 32256; which = 4; }
        else                { src = xp; local = g - 33792; which = 5; }
        float v = LD(src, local, dts[which]);
        if (which == 3) v = -__expf(v) * 1.44269504f;   // A2 = -exp(A_log)*log2e
        pf[g] = v;
    } else if (blk < 1860) {
        if (t == 0) dts[0] = detect_dtype(x);
        __syncthreads();
        const int dt = dts[0];
        size_t i = ((size_t)(blk - 324) * 256 + t) * 8;
        ushort4 o0, o1;
        if (dt == DT_F32) {
            float4 a = *(const float4*)((const float*)x + i);
            float4 b = *(const float4*)((const float*)x + i + 4);
            o0.x = f2bf(a.x); o0.y = f2bf(a.y); o0.z = f2bf(a.z); o0.w = f2bf(a.w);
            o1.x = f2bf(b.x); o1.y = f2bf(b.y); o1.z = f2bf(b.z); o1.w = f2bf(b.w);
        } else if (dt == DT_BF16) {
            o0 = *(const ushort4*)((const unsigned short*)x + i);
            o1 = *(const ushort4*)((const unsigned short*)x + i + 4);
        } else {
            o0 = (ushort4){0,0,0,0}; o1 = (ushort4){0,0,0,0};
        }
        *(ushort4*)&xb[i] = o0;
        *(ushort4*)&xb[i + 4] = o1;
    } else {
        const void* src; unsigned short* dst; int R, C, tx_n, idx;
        if (blk < 2436)      { src = in_w;  dst = inT;  R = 768;  C = 3072; tx_n = 48; idx = blk - 1860; }
        else if (blk < 3012) { src = dt_w;  dst = dtT;  R = 1536; C = 1536; tx_n = 24; idx = blk - 2436; }
        else                 { src = out_w; dst = outT; R = 1536; C = 768;  tx_n = 12; idx = blk - 3012; }
        if (t == 0) dts[0] = detect_dtype(src);
        __syncthreads();
        const int dt = dts[0];
        const int tx = t & 15, ty = t >> 4;          // 16 x 16 threads
        const int bx = (idx % tx_n) * 64, by = (idx / tx_n) * 64;
        #pragma unroll
        for (int i = 0; i < 4; ++i) {
            int rl = ty + i * 16;
            size_t soff = (size_t)(by + rl) * C + bx + tx * 4;
            ushort4 hv;
            if (dt == DT_F32) {
                float4 v = *(const float4*)((const float*)src + soff);
                hv.x = f2bf(v.x); hv.y = f2bf(v.y); hv.z = f2bf(v.z); hv.w = f2bf(v.w);
            } else if (dt == DT_BF16) {
                hv = *(const ushort4*)((const unsigned short*)src + soff);
            } else {
                hv = (ushort4){0,0,0,0};
            }
            *(ushort4*)&tile[rl][tx * 4] = hv;
        }
        __syncthreads();
        #pragma unroll
        for (int i = 0; i < 4; ++i) {
            int cl = ty + i * 16;
            int m0 = tx * 4;
            ushort4 o;
            o.x = tile[m0 + 0][cl]; o.y = tile[m0 + 1][cl];
            o.z = tile[m0 + 2][cl]; o.w = tile[m0 + 3][cl];
            *(ushort4*)&dst[(size_t)(bx + cl) * R + by + m0] = o;
        }
    }
}

// ---- MFMA GEMM: C = A[M][K] @ Bt[N][K]^T, 128x64 tile, BK=64, dbuf async ----
// (R20 structure, frozen.) Granule rotation: slot (row,g) holds k-granule
// (g - (row>>1)) & 3 within its 32-K panel.
// EPI 1: bf16 C0 = softplus(v + biasf[col])
// EPI 2: f32  C0 = v (final output)
// EPI 3: col < N/2 -> bf16 C0 = v ; else bf16 C1 = silu(v)
template<int EPI>
__global__ __launch_bounds__(256) void gemm_kernel(
    const unsigned short* __restrict__ A, const unsigned short* __restrict__ Bt,
    void* __restrict__ C0, void* __restrict__ C1, const float* __restrict__ biasf,
    int M, int N, int K)
{
    __shared__ __align__(16) unsigned short As[2][2][128 * 32];   // 32 KB
    __shared__ __align__(16) unsigned short Bs[2][2][64 * 32];    // 16 KB
    const int t    = threadIdx.x;
    const int m0   = blockIdx.x * 128;
    const int n0   = blockIdx.y * 64;
    const int w    = t >> 6;
    const int lane = t & 63;
    const int wm   = (w >> 1) * 64, wn = (w & 1) * 32;
    const int lm   = lane & 15, quad = lane >> 4;
    const int srow = lane >> 2;          // staging: row within 16-row group
    const int sg   = lane & 3;           // staging: granule slot

    f32x4 acc[4][2] = {};

    auto stage = [&](int k0, int q) {
        #pragma unroll
        for (int ph = 0; ph < 2; ++ph) {
            #pragma unroll
            for (int h = 0; h < 2; ++h) {
                int row = w * 32 + h * 16 + srow;
                int kg  = (sg - (row >> 1)) & 3;
                async_cp16((glob_us*)&A[(size_t)(m0 + row) * K + k0 + ph * 32 + kg * 8],
                           (lds_us*)&As[q][ph][(w * 32 + h * 16) * 32]);
            }
            int brow = w * 16 + srow;
            int bkg  = (sg - (brow >> 1)) & 3;
            async_cp16((glob_us*)&Bt[(size_t)(n0 + brow) * K + k0 + ph * 32 + bkg * 8],
                       (lds_us*)&Bs[q][ph][(w * 16) * 32]);
        }
    };

    // prologue: stage tile 0 into buffer 0
    stage(0, 0);

    int p = 0;
    for (int k0 = 0; k0 < K; k0 += 64) {
        __syncthreads();                       // drains stage(k0) into buf p
        if (k0 + 64 < K) stage(k0 + 64, p ^ 1);  // overlaps with 16 MFMAs below
        #pragma unroll
        for (int ph = 0; ph < 2; ++ph) {
            bf16x8 af[4], bfr[2];
            #pragma unroll
            for (int i = 0; i < 4; ++i) {
                int row = wm + i * 16 + lm;
                int g   = (quad + (row >> 1)) & 3;
                af[i] = *(const bf16x8*)&As[p][ph][row * 32 + g * 8];
            }
            #pragma unroll
            for (int j = 0; j < 2; ++j) {
                int row = wn + j * 16 + lm;
                int g   = (quad + (row >> 1)) & 3;
                bfr[j] = *(const bf16x8*)&Bs[p][ph][row * 32 + g * 8];
            }
            #pragma unroll
            for (int i = 0; i < 4; ++i)
                #pragma unroll
                for (int j = 0; j < 2; ++j)
                    acc[i][j] = __builtin_amdgcn_mfma_f32_16x16x32_bf16(af[i], bfr[j], acc[i][j], 0, 0, 0);
        }
        p ^= 1;
    }

    const int half = N >> 1;
    #pragma unroll
    for (int i = 0; i < 4; ++i) {
        #pragma unroll
        for (int j = 0; j < 2; ++j) {
            int col = n0 + wn + j * 16 + lm;
            #pragma unroll
            for (int r = 0; r < 4; ++r) {
                int row = m0 + wm + i * 16 + quad * 4 + r;
                float v = acc[i][j][r];
                if (EPI == 1) {
                    v += biasf[col];
                    float sp = (v > 20.f) ? v : log1pf(__expf(v));
                    ((unsigned short*)C0)[(size_t)row * N + col] = f2bf(sp);
                } else if (EPI == 2) {
                    ((float*)C0)[(size_t)row * N + col] = v;
                } else {
                    if (col < half) {
                        ((unsigned short*)C0)[(size_t)row * half + col] = f2bf(v);
                    } else {
                        float s = v / (1.f + __expf(-v));
                        ((unsigned short*)C1)[(size_t)row * half + col - half] = f2bf(s);
                    }
                }
            }
        }
    }
}

// ---- depthwise conv3 + bias + SiLU ----
__global__ __launch_bounds__(256) void conv_silu_kernel(
    const unsigned short* __restrict__ xcpre, const float* __restrict__ cwf,
    const float* __restrict__ cbf, unsigned short* __restrict__ xcb)
{
    int idx = blockIdx.x * 256 + threadIdx.x;
    int d   = idx % DINNER;
    int row = idx / DINNER;
    int l   = row % SEQL;
    size_t base = (size_t)row * DINNER + d;
    float acc = cbf[d];
    if (l > 0)        acc += bf2f(xcpre[base - DINNER]) * cwf[d * 3 + 0];
    acc += bf2f(xcpre[base]) * cwf[d * 3 + 1];
    if (l < SEQL - 1) acc += bf2f(xcpre[base + DINNER]) * cwf[d * 3 + 2];
    float s = acc / (1.f + __expf(-acc));
    xcb[base] = f2bf(s);
}

// ---- x_proj: BC[row][32] = xc[row][:] @ xproj_f[1536][32] ----
__global__ __launch_bounds__(128) void xproj_kernel(
    const unsigned short* __restrict__ xcb, const float* __restrict__ wf,
    float* __restrict__ BC)
{
    __shared__ float red[4][32][4];
    const int t = threadIdx.x;
    const int s = t & 31, part = t >> 5;
    const int row0 = blockIdx.x * 4;
    float acc[4] = {0.f, 0.f, 0.f, 0.f};
    for (int k = part * 384; k < (part + 1) * 384; ++k) {
        float wv = wf[k * 32 + s];
        #pragma unroll
        for (int r = 0; r < 4; ++r)
            acc[r] += bf2f(xcb[(size_t)(row0 + r) * DINNER + k]) * wv;
    }
    #pragma unroll
    for (int r = 0; r < 4; ++r) red[part][s][r] = acc[r];
    __syncthreads();
    if (t < 32) {
        #pragma unroll
        for (int r = 0; r < 4; ++r)
            BC[(size_t)(row0 + r) * 32 + t] =
                red[0][t][r] + red[1][t][r] + red[2][t][r] + red[3][t][r];
    }
}

// ====== LDS-staged chunked scan: block = 64 d x 4 q on one (b,chunk) ======
// Per 8-step group: wave w stages ONE 1KB panel via a single global_load_lds
// (w0 dlt, w1 xcb, w2 zg [phase C], last wave BC). 3-buffer rotation,
// counted vmcnt(1) + raw s_barrier. Safety: buf (g+2)%3 was last read at
// group g-1, and every wave passed barrier(g) only after finishing g-1.
__global__ __launch_bounds__(256) void scan_phase_a(
    const unsigned short* __restrict__ dlt, const unsigned short* __restrict__ xcb,
    const float* __restrict__ BC, const float* __restrict__ A_log_f,
    unsigned short* __restrict__ P, float* __restrict__ S)
{
    __shared__ __align__(16) unsigned short dS[3][8][64];   // 1.5 KB x 2
    __shared__ __align__(16) unsigned short xS[3][8][64];
    __shared__ __align__(16) float bS[3][8][32];            // 3 KB
    const int t    = threadIdx.x;
    const int w    = t >> 6, lane = t & 63;
    const int q    = t & 3,  dl   = t >> 2;      // d_local 0..63
    const int bid  = blockIdx.x;
    const int dg   = bid % 24;
    const int cc   = (bid / 24) % NCHUNK;
    const int b    = bid / (24 * NCHUNK);
    const int d0   = dg * 64;
    const int d    = d0 + dl;
    const int row0 = b * SEQL + cc * CHLEN;
    const int srow = lane >> 3, scol = lane & 7;

    f32x4 A2 = *(const f32x4*)&A_log_f[d * 16 + q * 4];
    f32x4 h = (f32x4){0.f, 0.f, 0.f, 0.f};
    float sdv = 0.f;

    auto stage = [&](int g, int buf) {
        int r = row0 + g * 8 + srow;
        if (w == 0)
            async_cp16((glob_us*)&dlt[(size_t)r * DINNER + d0 + scol * 8],
                       (lds_us*)&dS[buf][0][0] + lane * 8);
        else if (w == 1)
            async_cp16((glob_us*)&xcb[(size_t)r * DINNER + d0 + scol * 8],
                       (lds_us*)&xS[buf][0][0] + lane * 8);
        else if (w == 2)
            async_cp16((glob_us*)&BC[(size_t)r * 32 + scol * 4],
                       (lds_us*)&bS[buf][0][0] + lane * 8);
    };

    stage(0, 0);
    stage(1, 1);
    #pragma unroll
    for (int g = 0; g < 8; ++g) {
        if (g < 7) asm volatile("s_waitcnt vmcnt(1)" ::: "memory");
        else       asm volatile("s_waitcnt vmcnt(0)" ::: "memory");
        __builtin_amdgcn_s_barrier();
        __builtin_amdgcn_sched_barrier(0);
        if (g + 2 < 8) stage(g + 2, (g + 2) % 3);
        const int buf = g % 3;
        #pragma unroll
        for (int l = 0; l < 8; ++l) {
            float dv = bf2f(dS[buf][l][dl]);
            float xv = bf2f(xS[buf][l][dl]);
            float dx = dv * xv;
            sdv += dv;
            f32x4 Bv = *(const f32x4*)&bS[buf][l][q * 4];
            f32x4 e;
            e[0] = __builtin_amdgcn_exp2f(dv * A2[0]);
            e[1] = __builtin_amdgcn_exp2f(dv * A2[1]);
            e[2] = __builtin_amdgcn_exp2f(dv * A2[2]);
            e[3] = __builtin_amdgcn_exp2f(dv * A2[3]);
            h = e * h + dx * Bv;
        }
    }

    size_t idx = (((size_t)(b * NCHUNK + cc)) * DINNER + d) * 16 + q * 4;
    *(f32x4*)&S[idx] = h;
    ushort4 pq;
    pq.x = f2bf(__builtin_amdgcn_exp2f(sdv * A2[0]));
    pq.y = f2bf(__builtin_amdgcn_exp2f(sdv * A2[1]));
    pq.z = f2bf(__builtin_amdgcn_exp2f(sdv * A2[2]));
    pq.w = f2bf(__builtin_amdgcn_exp2f(sdv * A2[3]));
    *(ushort4*)&P[idx] = pq;
}

__global__ __launch_bounds__(256) void scan_combine(
    const unsigned short* __restrict__ P, float* __restrict__ S)
{
    int t = blockIdx.x * 256 + threadIdx.x;            // < 2*1536*16
    int b = t / (DINNER * NSTATE);
    int dn = t % (DINNER * NSTATE);
    const size_t stride = (size_t)(DINNER * NSTATE);
    size_t idx = (size_t)b * NCHUNK * stride + dn;
    float Pv = bf2f(P[idx]);
    float Sv = S[idx];
    float H = 0.f;
    for (int c = 0; c < NCHUNK; ++c) {
        float Pn = 0.f, Sn = 0.f;
        if (c + 1 < NCHUNK) {                  // prefetch next chunk
            Pn = bf2f(P[idx + stride]);
            Sn = S[idx + stride];
        }
        S[idx] = H;                 // Hin for chunk c
        H = Pv * H + Sv;
        Pv = Pn; Sv = Sn;
        idx += stride;
    }
}

__global__ __launch_bounds__(256) void scan_phase_c(
    const unsigned short* __restrict__ dlt, const unsigned short* __restrict__ xcb,
    const float* __restrict__ BC, const unsigned short* __restrict__ zg,
    const float* __restrict__ A_log_f, const float* __restrict__ D_f,
    const float* __restrict__ Hin, unsigned short* __restrict__ yg)
{
    __shared__ __align__(16) unsigned short dS[3][8][64];
    __shared__ __align__(16) unsigned short xS[3][8][64];
    __shared__ __align__(16) unsigned short zS[3][8][64];
    __shared__ __align__(16) float bS[3][8][32];
    const int t    = threadIdx.x;
    const int w    = t >> 6, lane = t & 63;
    const int q    = t & 3,  dl   = t >> 2;
    const int bid  = blockIdx.x;
    const int dg   = bid % 24;
    const int cc   = (bid / 24) % NCHUNK;
    const int b    = bid / (24 * NCHUNK);
    const int d0   = dg * 64;
    const int d    = d0 + dl;
    const int row0 = b * SEQL + cc * CHLEN;
    const int srow = lane >> 3, scol = lane & 7;

    f32x4 A2 = *(const f32x4*)&A_log_f[d * 16 + q * 4];
    size_t hidx = (((size_t)(b * NCHUNK + cc)) * DINNER + d) * 16 + q * 4;
    f32x4 h = *(const f32x4*)&Hin[hidx];
    const float Dd = D_f[d];

    auto stage = [&](int g, int buf) {
        int r = row0 + g * 8 + srow;
        if (w == 0)
            async_cp16((glob_us*)&dlt[(size_t)r * DINNER + d0 + scol * 8],
                       (lds_us*)&dS[buf][0][0] + lane * 8);
        else if (w == 1)
            async_cp16((glob_us*)&xcb[(size_t)r * DINNER + d0 + scol * 8],
                       (lds_us*)&xS[buf][0][0] + lane * 8);
        else if (w == 2)
            async_cp16((glob_us*)&zg[(size_t)r * DINNER + d0 + scol * 8],
                       (lds_us*)&zS[buf][0][0] + lane * 8);
        else
            async_cp16((glob_us*)&BC[(size_t)r * 32 + scol * 4],
                       (lds_us*)&bS[buf][0][0] + lane * 8);
    };

    stage(0, 0);
    stage(1, 1);
    #pragma unroll
    for (int g = 0; g < 8; ++g) {
        if (g < 7) asm volatile("s_waitcnt vmcnt(1)" ::: "memory");
        else       asm volatile("s_waitcnt vmcnt(0)" ::: "memory");
        __builtin_amdgcn_s_barrier();
        __builtin_amdgcn_sched_barrier(0);
        if (g + 2 < 8) stage(g + 2, (g + 2) % 3);
        const int buf = g % 3;
        #pragma unroll
        for (int l = 0; l < 8; ++l) {
            float dv = bf2f(dS[buf][l][dl]);
            float xv = bf2f(xS[buf][l][dl]);
            float dx = dv * xv;
            f32x4 Bv = *(const f32x4*)&bS[buf][l][q * 4];
            f32x4 Cv = *(const f32x4*)&bS[buf][l][16 + q * 4];
            f32x4 e;
            e[0] = __builtin_amdgcn_exp2f(dv * A2[0]);
            e[1] = __builtin_amdgcn_exp2f(dv * A2[1]);
            e[2] = __builtin_amdgcn_exp2f(dv * A2[2]);
            e[3] = __builtin_amdgcn_exp2f(dv * A2[3]);
            h = e * h + dx * Bv;
            f32x4 yv = h * Cv;
            float y = yv[0] + yv[1] + yv[2] + yv[3];
            y += __shfl_xor(y, 1);
            y += __shfl_xor(y, 2);
            if ((l & 3) == q) {              // rotated store: lane q owns step l
                float zv = bf2f(zS[buf][l][dl]);
                yg[(size_t)(row0 + g * 8 + l) * DINNER + d] = f2bf((y + Dd * xv) * zv);
            }
        }
    }
}

__global__ void guard_kernel(float* out, int code)
{
    if (threadIdx.x == 0 && blockIdx.x == 0 && code) out[0] = (float)code;
}

extern "C" void kernel_launch(void* const* d_in, const int* in_sizes, int n_in,
                              void* d_out, int out_size, void* d_ws, size_t ws_size,
                              hipStream_t stream) {
    static const int EXPECTED[10] = {3145728, 2359296, 4608, 1536, 49152,
                                     2359296, 1536, 24576, 1536, 1179648};
    bool ok = (n_in == 10);
    if (ok) for (int i = 0; i < 10; ++i) ok = ok && (in_sizes[i] == EXPECTED[i]);
    int code = 0;
    if (!ok) code = 2000;
    else if (ws_size < 67895296ULL) code = 3000;
    if (code) { guard_kernel<<<1, 64, 0, stream>>>((float*)d_out, code); return; }

    const void* x       = d_in[0];
    const void* in_w    = d_in[1];
    const void* conv_w  = d_in[2];
    const void* conv_b  = d_in[3];
    const void* xproj_w = d_in[4];
    const void* dt_w    = d_in[5];
    const void* dt_b    = d_in[6];
    const void* A_log   = d_in[7];
    const void* Dvec    = d_in[8];
    const void* out_w   = d_in[9];

    char* ws = (char*)d_ws;
    float* conv_w_f = (float*)(ws + 0);        // 4608
    float* conv_b_f = (float*)(ws + 18432);    // 1536
    float* dt_b_f   = (float*)(ws + 24576);    // 1536
    float* A_log_f  = (float*)(ws + 30720);    // 24576 (holds A2 = -exp(A_log)*log2e)
    float* D_f      = (float*)(ws + 129024);   // 1536
    float* xproj_f  = (float*)(ws + 135168);   // 49152
    unsigned short* xb    = (unsigned short*)(ws + 524288);    // [4096][768]  (dead after gemm1)
    unsigned short* inT   = (unsigned short*)(ws + 6815744);   // [3072][768]  (dead after gemm1)
    unsigned short* yg    = (unsigned short*)(ws + 524288);    // [4096][1536] alias xb+inT
    unsigned short* dtT   = (unsigned short*)(ws + 13107200);  // [1536][1536]
    unsigned short* outT  = (unsigned short*)(ws + 17825792);  // [768][1536]
    unsigned short* xcpre = (unsigned short*)(ws + 20185088);  // [4096][1536] (dead after conv)
    unsigned short* dlt   = xcpre;                             // alias (gemm2 out)
    float*          BC    = (float*)(ws + 32768000);           // [4096][32]
    unsigned short* zg    = (unsigned short*)(ws + 33292288);  // [4096][1536] silu(z)
    unsigned short* xcb   = (unsigned short*)(ws + 45875200);  // [4096][1536]
    float*          scanS = (float*)(ws + 58458112);           // [2][32][1536][16] f32 6.29MB
    unsigned short* scanP = (unsigned short*)(ws + 64749568);  // same shape bf16   3.15MB

    prep_kernel<<<3300, 256, 0, stream>>>(x, in_w, conv_w, conv_b, xproj_w, dt_w,
                                          dt_b, A_log, Dvec, out_w,
                                          xb, inT, dtT, outT, (float*)ws);

    gemm_kernel<3><<<dim3(32, 48), 256, 0, stream>>>(xb, inT, (void*)xcpre, (void*)zg,
                                                     nullptr, 4096, 3072, 768);
    conv_silu_kernel<<<(4096 * DINNER) / 256, 256, 0, stream>>>(xcpre, conv_w_f, conv_b_f, xcb);
    xproj_kernel<<<1024, 128, 0, stream>>>(xcb, xproj_f, BC);
    gemm_kernel<1><<<dim3(32, 24), 256, 0, stream>>>(xcb, dtT, (void*)dlt, nullptr,
                                                     dt_b_f, 4096, 1536, 1536);
    scan_phase_a<<<1536, 256, 0, stream>>>(dlt, xcb, BC, A_log_f, scanP, scanS);
    scan_combine<<<192, 256, 0, stream>>>(scanP, scanS);
    scan_phase_c<<<1536, 256, 0, stream>>>(dlt, xcb, BC, zg, A_log_f, D_f, scanS, yg);
    gemm_kernel<2><<<dim3(32, 12), 256, 0, stream>>>(yg, outT, d_out, nullptr,
                                                    nullptr, 4096, 768, 1536);
}

// Round 9
// 316.558 us; speedup vs baseline: 1.0279x; 1.0279x over previous
//
#include <hip/hip_runtime.h>
#include <cmath>

// SimplifiedSSM: B=2, L=2048, d_model=768, d_state=16, d_inner=1536
// ROUND 23: scans back to R21 register ping-pong (R22 LDS staging neutral ->
// reverted) + NEW 2-d-per-thread packing: each thread owns 2 adjacent d x 4
// states. Halves requests/d (packed 4B dv/xv/zv, shared 16B Bv/Cv), ~35%
// fewer inst/d, DPP quad-perm reduce (VALU) replaces shfl (LDS pipe).
// Grid 768 blocks (3/CU). conv_silu vectorized 8 d/thread with plane-
// transposed weights (done in prep). GEMMs/prep/xproj/combine frozen.
#define DMODEL 768
#define DINNER 1536
#define NSTATE 16
#define SEQL   2048
#define NCHUNK 32
#define CHLEN  64      // SEQL / NCHUNK

#define DT_F32  0
#define DT_BF16 1
#define DT_ZERO 2

typedef __bf16 bf16x8 __attribute__((ext_vector_type(8)));
typedef float  f32x4  __attribute__((ext_vector_type(4)));

typedef __attribute__((address_space(3))) unsigned short lds_us;
typedef const __attribute__((address_space(1))) unsigned short glob_us;

__device__ __forceinline__ void async_cp16(glob_us* g, lds_us* l) {
    __builtin_amdgcn_global_load_lds((const __attribute__((address_space(1))) void*)g,
                                     (__attribute__((address_space(3))) void*)l, 16, 0, 0);
}

__device__ __forceinline__ float bf2f(unsigned short h) {
    union { unsigned u; float f; } v; v.u = ((unsigned)h) << 16; return v.f;
}
__device__ __forceinline__ float bflo(unsigned p) {
    union { unsigned u; float f; } v; v.u = p << 16; return v.f;
}
__device__ __forceinline__ float bfhi(unsigned p) {
    union { unsigned u; float f; } v; v.u = p & 0xFFFF0000u; return v.f;
}
__device__ __forceinline__ unsigned short f2bf(float f) {
    union { float f; unsigned u; } v; v.f = f;
    unsigned r = (v.u + 0x7FFFu + ((v.u >> 16) & 1u)) >> 16;
    return (unsigned short)r;
}
// butterfly sum over 4-lane quads via DPP (all lanes get the total)
__device__ __forceinline__ float quad_reduce(float y) {
    int yi = __float_as_int(y);
    y += __int_as_float(__builtin_amdgcn_mov_dpp(yi, 0xB1, 0xF, 0xF, true)); // quad_perm [1,0,3,2]
    yi = __float_as_int(y);
    y += __int_as_float(__builtin_amdgcn_mov_dpp(yi, 0x4E, 0xF, 0xF, true)); // quad_perm [2,3,0,1]
    return y;
}
__device__ int detect_dtype(const void* p) {
    const unsigned* u = (const unsigned*)p;
    int nzlo = 0, band = 0, anynz = 0;
    for (int i = 0; i < 64; ++i) {
        unsigned w = u[i];
        anynz |= (w != 0);
        unsigned lo = w & 0xFFFFu;
        if (lo) {
            ++nzlo;
            unsigned e8 = (lo >> 7) & 0xFF;
            if (e8 >= 0x60 && e8 <= 0x8E) ++band;
        }
    }
    if (nzlo >= 8) return (band * 2 > nzlo) ? DT_BF16 : DT_F32;
    return anynz ? DT_F32 : DT_ZERO;
}
__device__ __forceinline__ float LD(const void* p, size_t i, int dt) {
    if (dt == DT_BF16) return bf2f(((const unsigned short*)p)[i]);
    if (dt == DT_F32)  return ((const float*)p)[i];
    return 0.f;
}

// ---- fused prep: params->f32 (A_log -> A2, conv_w -> 3 planes) | x->bf16 |
//      3 weight transposes ----
// blocks: [0,324) params, [324,1860) x (8 elem/thread),
//         [1860,2436) in_w, [2436,3012) dt_w, [3012,3300) out_w (64x64 tiles)
__global__ __launch_bounds__(256) void prep_kernel(
    const void* __restrict__ x, const void* __restrict__ in_w,
    const void* __restrict__ cw, const void* __restrict__ cb,
    const void* __restrict__ xp, const void* __restrict__ dt_w,
    const void* __restrict__ db, const void* __restrict__ Al,
    const void* __restrict__ Dv, const void* __restrict__ out_w,
    unsigned short* __restrict__ xb, unsigned short* __restrict__ inT,
    unsigned short* __restrict__ dtT, unsigned short* __restrict__ outT,
    float* __restrict__ pf)
{
    __shared__ unsigned short tile[64][68];
    __shared__ int dts[6];
    const int blk = blockIdx.x;
    const int t   = threadIdx.x;

    if (blk < 324) {
        if (t == 0) {
            dts[0] = detect_dtype(cw); dts[1] = detect_dtype(cb);
            dts[2] = detect_dtype(db); dts[3] = detect_dtype(Al);
            dts[4] = detect_dtype(Dv); dts[5] = detect_dtype(xp);
        }
        __syncthreads();
        int g = blk * 256 + t;
        if (g >= 82944) return;
        const void* src; int local; int which;
        if      (g <  4608) { src = cw; local = g;         which = 0; }
        else if (g <  6144) { src = cb; local = g - 4608;  which = 1; }
        else if (g <  7680) { src = db; local = g - 6144;  which = 2; }
        else if (g < 32256) { src = Al; local = g - 7680;  which = 3; }
        else if (g < 33792) { src = Dv; local = g - 32256; which = 4; }
        else                { src = xp; local = g - 33792; which = 5; }
        float v = LD(src, local, dts[which]);
        int out = g;
        if (which == 3) v = -__expf(v) * 1.44269504f;   // A2 = -exp(A_log)*log2e
        if (which == 0) out = (local % 3) * DINNER + local / 3;  // conv planes
        pf[out] = v;
    } else if (blk < 1860) {
        if (t == 0) dts[0] = detect_dtype(x);
        __syncthreads();
        const int dt = dts[0];
        size_t i = ((size_t)(blk - 324) * 256 + t) * 8;
        ushort4 o0, o1;
        if (dt == DT_F32) {
            float4 a = *(const float4*)((const float*)x + i);
            float4 b = *(const float4*)((const float*)x + i + 4);
            o0.x = f2bf(a.x); o0.y = f2bf(a.y); o0.z = f2bf(a.z); o0.w = f2bf(a.w);
            o1.x = f2bf(b.x); o1.y = f2bf(b.y); o1.z = f2bf(b.z); o1.w = f2bf(b.w);
        } else if (dt == DT_BF16) {
            o0 = *(const ushort4*)((const unsigned short*)x + i);
            o1 = *(const ushort4*)((const unsigned short*)x + i + 4);
        } else {
            o0 = (ushort4){0,0,0,0}; o1 = (ushort4){0,0,0,0};
        }
        *(ushort4*)&xb[i] = o0;
        *(ushort4*)&xb[i + 4] = o1;
    } else {
        const void* src; unsigned short* dst; int R, C, tx_n, idx;
        if (blk < 2436)      { src = in_w;  dst = inT;  R = 768;  C = 3072; tx_n = 48; idx = blk - 1860; }
        else if (blk < 3012) { src = dt_w;  dst = dtT;  R = 1536; C = 1536; tx_n = 24; idx = blk - 2436; }
        else                 { src = out_w; dst = outT; R = 1536; C = 768;  tx_n = 12; idx = blk - 3012; }
        if (t == 0) dts[0] = detect_dtype(src);
        __syncthreads();
        const int dt = dts[0];
        const int tx = t & 15, ty = t >> 4;          // 16 x 16 threads
        const int bx = (idx % tx_n) * 64, by = (idx / tx_n) * 64;
        #pragma unroll
        for (int i = 0; i < 4; ++i) {
            int rl = ty + i * 16;
            size_t soff = (size_t)(by + rl) * C + bx + tx * 4;
            ushort4 hv;
            if (dt == DT_F32) {
                float4 v = *(const float4*)((const float*)src + soff);
                hv.x = f2bf(v.x); hv.y = f2bf(v.y); hv.z = f2bf(v.z); hv.w = f2bf(v.w);
            } else if (dt == DT_BF16) {
                hv = *(const ushort4*)((const unsigned short*)src + soff);
            } else {
                hv = (ushort4){0,0,0,0};
            }
            *(ushort4*)&tile[rl][tx * 4] = hv;
        }
        __syncthreads();
        #pragma unroll
        for (int i = 0; i < 4; ++i) {
            int cl = ty + i * 16;
            int m0 = tx * 4;
            ushort4 o;
            o.x = tile[m0 + 0][cl]; o.y = tile[m0 + 1][cl];
            o.z = tile[m0 + 2][cl]; o.w = tile[m0 + 3][cl];
            *(ushort4*)&dst[(size_t)(bx + cl) * R + by + m0] = o;
        }
    }
}

// ---- MFMA GEMM: C = A[M][K] @ Bt[N][K]^T, 128x64 tile, BK=64, dbuf async ----
// (R20 structure, frozen.) Granule rotation: slot (row,g) holds k-granule
// (g - (row>>1)) & 3 within its 32-K panel.
// EPI 1: bf16 C0 = softplus(v + biasf[col])
// EPI 2: f32  C0 = v (final output)
// EPI 3: col < N/2 -> bf16 C0 = v ; else bf16 C1 = silu(v)
template<int EPI>
__global__ __launch_bounds__(256) void gemm_kernel(
    const unsigned short* __restrict__ A, const unsigned short* __restrict__ Bt,
    void* __restrict__ C0, void* __restrict__ C1, const float* __restrict__ biasf,
    int M, int N, int K)
{
    __shared__ __align__(16) unsigned short As[2][2][128 * 32];   // 32 KB
    __shared__ __align__(16) unsigned short Bs[2][2][64 * 32];    // 16 KB
    const int t    = threadIdx.x;
    const int m0   = blockIdx.x * 128;
    const int n0   = blockIdx.y * 64;
    const int w    = t >> 6;
    const int lane = t & 63;
    const int wm   = (w >> 1) * 64, wn = (w & 1) * 32;
    const int lm   = lane & 15, quad = lane >> 4;
    const int srow = lane >> 2;          // staging: row within 16-row group
    const int sg   = lane & 3;           // staging: granule slot

    f32x4 acc[4][2] = {};

    auto stage = [&](int k0, int q) {
        #pragma unroll
        for (int ph = 0; ph < 2; ++ph) {
            #pragma unroll
            for (int h = 0; h < 2; ++h) {
                int row = w * 32 + h * 16 + srow;
                int kg  = (sg - (row >> 1)) & 3;
                async_cp16((glob_us*)&A[(size_t)(m0 + row) * K + k0 + ph * 32 + kg * 8],
                           (lds_us*)&As[q][ph][(w * 32 + h * 16) * 32]);
            }
            int brow = w * 16 + srow;
            int bkg  = (sg - (brow >> 1)) & 3;
            async_cp16((glob_us*)&Bt[(size_t)(n0 + brow) * K + k0 + ph * 32 + bkg * 8],
                       (lds_us*)&Bs[q][ph][(w * 16) * 32]);
        }
    };

    // prologue: stage tile 0 into buffer 0
    stage(0, 0);

    int p = 0;
    for (int k0 = 0; k0 < K; k0 += 64) {
        __syncthreads();                       // drains stage(k0) into buf p
        if (k0 + 64 < K) stage(k0 + 64, p ^ 1);  // overlaps with 16 MFMAs below
        #pragma unroll
        for (int ph = 0; ph < 2; ++ph) {
            bf16x8 af[4], bfr[2];
            #pragma unroll
            for (int i = 0; i < 4; ++i) {
                int row = wm + i * 16 + lm;
                int g   = (quad + (row >> 1)) & 3;
                af[i] = *(const bf16x8*)&As[p][ph][row * 32 + g * 8];
            }
            #pragma unroll
            for (int j = 0; j < 2; ++j) {
                int row = wn + j * 16 + lm;
                int g   = (quad + (row >> 1)) & 3;
                bfr[j] = *(const bf16x8*)&Bs[p][ph][row * 32 + g * 8];
            }
            #pragma unroll
            for (int i = 0; i < 4; ++i)
                #pragma unroll
                for (int j = 0; j < 2; ++j)
                    acc[i][j] = __builtin_amdgcn_mfma_f32_16x16x32_bf16(af[i], bfr[j], acc[i][j], 0, 0, 0);
        }
        p ^= 1;
    }

    const int half = N >> 1;
    #pragma unroll
    for (int i = 0; i < 4; ++i) {
        #pragma unroll
        for (int j = 0; j < 2; ++j) {
            int col = n0 + wn + j * 16 + lm;
            #pragma unroll
            for (int r = 0; r < 4; ++r) {
                int row = m0 + wm + i * 16 + quad * 4 + r;
                float v = acc[i][j][r];
                if (EPI == 1) {
                    v += biasf[col];
                    float sp = (v > 20.f) ? v : log1pf(__expf(v));
                    ((unsigned short*)C0)[(size_t)row * N + col] = f2bf(sp);
                } else if (EPI == 2) {
                    ((float*)C0)[(size_t)row * N + col] = v;
                } else {
                    if (col < half) {
                        ((unsigned short*)C0)[(size_t)row * half + col] = f2bf(v);
                    } else {
                        float s = v / (1.f + __expf(-v));
                        ((unsigned short*)C1)[(size_t)row * half + col - half] = f2bf(s);
                    }
                }
            }
        }
    }
}

// ---- depthwise conv3 + bias + SiLU, 8 d/thread, plane weights ----
__global__ __launch_bounds__(256) void conv_silu_kernel(
    const unsigned short* __restrict__ xcpre, const float* __restrict__ cwf,
    const float* __restrict__ cbf, unsigned short* __restrict__ xcb)
{
    const float* cw0 = cwf;
    const float* cw1 = cwf + DINNER;
    const float* cw2 = cwf + 2 * DINNER;
    size_t idx = ((size_t)blockIdx.x * 256 + threadIdx.x) * 8;
    int d8  = (int)(idx % DINNER);
    int row = (int)(idx / DINNER);
    int l   = row % SEQL;
    size_t base = (size_t)row * DINNER + d8;
    uint4 zero = {0, 0, 0, 0};
    uint4 xm = (l > 0)        ? *(const uint4*)&xcpre[base - DINNER] : zero;
    uint4 x0 = *(const uint4*)&xcpre[base];
    uint4 xp = (l < SEQL - 1) ? *(const uint4*)&xcpre[base + DINNER] : zero;
    float4 c0a = *(const float4*)&cw0[d8], c0b = *(const float4*)&cw0[d8 + 4];
    float4 c1a = *(const float4*)&cw1[d8], c1b = *(const float4*)&cw1[d8 + 4];
    float4 c2a = *(const float4*)&cw2[d8], c2b = *(const float4*)&cw2[d8 + 4];
    float4 cba = *(const float4*)&cbf[d8], cbb = *(const float4*)&cbf[d8 + 4];
    const unsigned* mw = (const unsigned*)&xm;
    const unsigned* zw = (const unsigned*)&x0;
    const unsigned* pw = (const unsigned*)&xp;
    const float* C0 = (const float*)&c0a;  // c0a,c0b contiguous on stack? use arrays
    float w0[8] = {c0a.x, c0a.y, c0a.z, c0a.w, c0b.x, c0b.y, c0b.z, c0b.w};
    float w1[8] = {c1a.x, c1a.y, c1a.z, c1a.w, c1b.x, c1b.y, c1b.z, c1b.w};
    float w2[8] = {c2a.x, c2a.y, c2a.z, c2a.w, c2b.x, c2b.y, c2b.z, c2b.w};
    float bb[8] = {cba.x, cba.y, cba.z, cba.w, cbb.x, cbb.y, cbb.z, cbb.w};
    (void)C0;
    unsigned short out[8];
    #pragma unroll
    for (int k = 0; k < 8; ++k) {
        unsigned wm_ = mw[k >> 1], wz = zw[k >> 1], wp = pw[k >> 1];
        float a = (k & 1) ? bfhi(wm_) : bflo(wm_);
        float c = (k & 1) ? bfhi(wz)  : bflo(wz);
        float e = (k & 1) ? bfhi(wp)  : bflo(wp);
        float acc = bb[k] + a * w0[k] + c * w1[k] + e * w2[k];
        float s = acc / (1.f + __expf(-acc));
        out[k] = f2bf(s);
    }
    *(uint4*)&xcb[base] = *(uint4*)out;
}

// ---- x_proj: BC[row][32] = xc[row][:] @ xproj_f[1536][32] ----
__global__ __launch_bounds__(128) void xproj_kernel(
    const unsigned short* __restrict__ xcb, const float* __restrict__ wf,
    float* __restrict__ BC)
{
    __shared__ float red[4][32][4];
    const int t = threadIdx.x;
    const int s = t & 31, part = t >> 5;
    const int row0 = blockIdx.x * 4;
    float acc[4] = {0.f, 0.f, 0.f, 0.f};
    for (int k = part * 384; k < (part + 1) * 384; ++k) {
        float wv = wf[k * 32 + s];
        #pragma unroll
        for (int r = 0; r < 4; ++r)
            acc[r] += bf2f(xcb[(size_t)(row0 + r) * DINNER + k]) * wv;
    }
    #pragma unroll
    for (int r = 0; r < 4; ++r) red[part][s][r] = acc[r];
    __syncthreads();
    if (t < 32) {
        #pragma unroll
        for (int r = 0; r < 4; ++r)
            BC[(size_t)(row0 + r) * 32 + t] =
                red[0][t][r] + red[1][t][r] + red[2][t][r] + red[3][t][r];
    }
}

// ====== chunked scan, q-split x 2-d-per-thread, register ping-pong ======
// Thread: q = t&3 owns states [4q,4q+4) of d and d+1 (d = 2*(dg*64 + t>>2)).
// Packed 4B dv/xv loads (2 bf16), shared Bv/Cv per step, DPP quad reduce.
struct GrpA { unsigned dv2[4], xv2[4]; f32x4 Bv[4]; };
struct GrpC { unsigned dv2[4], xv2[4]; f32x4 Bv[4], Cv[4]; };

__device__ __forceinline__ void ldA(GrpA& gp, const unsigned short* pd,
    const unsigned short* px, const float* pbc, int l) {
    #pragma unroll
    for (int j = 0; j < 4; ++j) {
        size_t o = (size_t)(l + j) * DINNER;
        gp.dv2[j] = *(const unsigned*)&pd[o];
        gp.xv2[j] = *(const unsigned*)&px[o];
        gp.Bv[j]  = *(const f32x4*)&pbc[(size_t)(l + j) * 32];
    }
}
__device__ __forceinline__ void ldC(GrpC& gp, const unsigned short* pd,
    const unsigned short* px, const float* pbc, int l) {
    #pragma unroll
    for (int j = 0; j < 4; ++j) {
        size_t o = (size_t)(l + j) * DINNER;
        gp.dv2[j] = *(const unsigned*)&pd[o];
        gp.xv2[j] = *(const unsigned*)&px[o];
        gp.Bv[j]  = *(const f32x4*)&pbc[(size_t)(l + j) * 32];
        gp.Cv[j]  = *(const f32x4*)&pbc[(size_t)(l + j) * 32 + 16];
    }
}
__device__ __forceinline__ void stepA(const GrpA& gp, const f32x4 A2a,
    const f32x4 A2b, f32x4& h0, f32x4& h1, float& sdv0, float& sdv1) {
    #pragma unroll
    for (int j = 0; j < 4; ++j) {
        float dv0 = bflo(gp.dv2[j]), dv1 = bfhi(gp.dv2[j]);
        float xv0 = bflo(gp.xv2[j]), xv1 = bfhi(gp.xv2[j]);
        sdv0 += dv0; sdv1 += dv1;
        f32x4 Bv = gp.Bv[j];
        f32x4 e0, e1;
        e0[0] = __builtin_amdgcn_exp2f(dv0 * A2a[0]);
        e0[1] = __builtin_amdgcn_exp2f(dv0 * A2a[1]);
        e0[2] = __builtin_amdgcn_exp2f(dv0 * A2a[2]);
        e0[3] = __builtin_amdgcn_exp2f(dv0 * A2a[3]);
        e1[0] = __builtin_amdgcn_exp2f(dv1 * A2b[0]);
        e1[1] = __builtin_amdgcn_exp2f(dv1 * A2b[1]);
        e1[2] = __builtin_amdgcn_exp2f(dv1 * A2b[2]);
        e1[3] = __builtin_amdgcn_exp2f(dv1 * A2b[3]);
        h0 = e0 * h0 + (dv0 * xv0) * Bv;
        h1 = e1 * h1 + (dv1 * xv1) * Bv;
    }
}

__global__ __launch_bounds__(256) void scan_phase_a(
    const unsigned short* __restrict__ dlt, const unsigned short* __restrict__ xcb,
    const float* __restrict__ BC, const float* __restrict__ A_log_f,
    unsigned short* __restrict__ P, float* __restrict__ S)
{
    const int t   = threadIdx.x;
    const int q   = t & 3;
    const int dpl = t >> 2;                       // 0..63
    const int bid = blockIdx.x;
    const int dg  = bid % 12;
    const int cc  = (bid / 12) % NCHUNK;
    const int b   = bid / (12 * NCHUNK);
    const int d   = (dg * 64 + dpl) * 2;
    f32x4 A2a = *(const f32x4*)&A_log_f[d * 16 + q * 4];
    f32x4 A2b = *(const f32x4*)&A_log_f[(d + 1) * 16 + q * 4];
    f32x4 h0 = (f32x4){0.f, 0.f, 0.f, 0.f};
    f32x4 h1 = (f32x4){0.f, 0.f, 0.f, 0.f};
    float sdv0 = 0.f, sdv1 = 0.f;
    const int row0 = b * SEQL + cc * CHLEN;
    const unsigned short* pd = dlt + (size_t)row0 * DINNER + d;
    const unsigned short* px = xcb + (size_t)row0 * DINNER + d;
    const float* pbc = BC + (size_t)row0 * 32 + q * 4;

    GrpA ga, gb;
    ldA(ga, pd, px, pbc, 0);
    for (int l0 = 0; l0 < CHLEN; l0 += 8) {
        ldA(gb, pd, px, pbc, l0 + 4);
        stepA(ga, A2a, A2b, h0, h1, sdv0, sdv1);
        if (l0 + 8 < CHLEN) ldA(ga, pd, px, pbc, l0 + 8);
        stepA(gb, A2a, A2b, h0, h1, sdv0, sdv1);
    }

    size_t idx = (((size_t)(b * NCHUNK + cc)) * DINNER + d) * 16 + q * 4;
    *(f32x4*)&S[idx] = h0;
    *(f32x4*)&S[idx + 16] = h1;
    ushort4 p0, p1;
    p0.x = f2bf(__builtin_amdgcn_exp2f(sdv0 * A2a[0]));
    p0.y = f2bf(__builtin_amdgcn_exp2f(sdv0 * A2a[1]));
    p0.z = f2bf(__builtin_amdgcn_exp2f(sdv0 * A2a[2]));
    p0.w = f2bf(__builtin_amdgcn_exp2f(sdv0 * A2a[3]));
    p1.x = f2bf(__builtin_amdgcn_exp2f(sdv1 * A2b[0]));
    p1.y = f2bf(__builtin_amdgcn_exp2f(sdv1 * A2b[1]));
    p1.z = f2bf(__builtin_amdgcn_exp2f(sdv1 * A2b[2]));
    p1.w = f2bf(__builtin_amdgcn_exp2f(sdv1 * A2b[3]));
    *(ushort4*)&P[idx] = p0;
    *(ushort4*)&P[idx + 16] = p1;
}

__global__ __launch_bounds__(256) void scan_combine(
    const unsigned short* __restrict__ P, float* __restrict__ S)
{
    int t = blockIdx.x * 256 + threadIdx.x;            // < 2*1536*16
    int b = t / (DINNER * NSTATE);
    int dn = t % (DINNER * NSTATE);
    const size_t stride = (size_t)(DINNER * NSTATE);
    size_t idx = (size_t)b * NCHUNK * stride + dn;
    float Pv = bf2f(P[idx]);
    float Sv = S[idx];
    float H = 0.f;
    for (int c = 0; c < NCHUNK; ++c) {
        float Pn = 0.f, Sn = 0.f;
        if (c + 1 < NCHUNK) {                  // prefetch next chunk
            Pn = bf2f(P[idx + stride]);
            Sn = S[idx + stride];
        }
        S[idx] = H;                 // Hin for chunk c
        H = Pv * H + Sv;
        Pv = Pn; Sv = Sn;
        idx += stride;
    }
}

__global__ __launch_bounds__(256) void scan_phase_c(
    const unsigned short* __restrict__ dlt, const unsigned short* __restrict__ xcb,
    const float* __restrict__ BC, const unsigned short* __restrict__ zg,
    const float* __restrict__ A_log_f, const float* __restrict__ D_f,
    const float* __restrict__ Hin, unsigned short* __restrict__ yg)
{
    const int t   = threadIdx.x;
    const int q   = t & 3;
    const int dpl = t >> 2;
    const int bid = blockIdx.x;
    const int dg  = bid % 12;
    const int cc  = (bid / 12) % NCHUNK;
    const int b   = bid / (12 * NCHUNK);
    const int d   = (dg * 64 + dpl) * 2;
    f32x4 A2a = *(const f32x4*)&A_log_f[d * 16 + q * 4];
    f32x4 A2b = *(const f32x4*)&A_log_f[(d + 1) * 16 + q * 4];
    size_t hidx = (((size_t)(b * NCHUNK + cc)) * DINNER + d) * 16 + q * 4;
    f32x4 h0 = *(const f32x4*)&Hin[hidx];
    f32x4 h1 = *(const f32x4*)&Hin[hidx + 16];
    const float Dd0 = D_f[d], Dd1 = D_f[d + 1];
    const int row0 = b * SEQL + cc * CHLEN;
    const unsigned short* pd = dlt + (size_t)row0 * DINNER + d;
    const unsigned short* px = xcb + (size_t)row0 * DINNER + d;
    const unsigned short* pz = zg  + (size_t)row0 * DINNER + d;
    unsigned short* py = yg + (size_t)row0 * DINNER + d;
    const float* pbc = BC + (size_t)row0 * 32 + q * 4;

    GrpC ga, gb;
    auto stepC = [&](const GrpC& gp, int l) {
        #pragma unroll
        for (int j = 0; j < 4; ++j) {
            float dv0 = bflo(gp.dv2[j]), dv1 = bfhi(gp.dv2[j]);
            float xv0 = bflo(gp.xv2[j]), xv1 = bfhi(gp.xv2[j]);
            f32x4 Bv = gp.Bv[j], Cv = gp.Cv[j];
            f32x4 e0, e1;
            e0[0] = __builtin_amdgcn_exp2f(dv0 * A2a[0]);
            e0[1] = __builtin_amdgcn_exp2f(dv0 * A2a[1]);
            e0[2] = __builtin_amdgcn_exp2f(dv0 * A2a[2]);
            e0[3] = __builtin_amdgcn_exp2f(dv0 * A2a[3]);
            e1[0] = __builtin_amdgcn_exp2f(dv1 * A2b[0]);
            e1[1] = __builtin_amdgcn_exp2f(dv1 * A2b[1]);
            e1[2] = __builtin_amdgcn_exp2f(dv1 * A2b[2]);
            e1[3] = __builtin_amdgcn_exp2f(dv1 * A2b[3]);
            h0 = e0 * h0 + (dv0 * xv0) * Bv;
            h1 = e1 * h1 + (dv1 * xv1) * Bv;
            f32x4 y0v = h0 * Cv;
            f32x4 y1v = h1 * Cv;
            float y0 = quad_reduce(y0v[0] + y0v[1] + y0v[2] + y0v[3]);
            float y1 = quad_reduce(y1v[0] + y1v[1] + y1v[2] + y1v[3]);
            if (j == q) {                      // rotated store: lane q owns step j
                unsigned zp = *(const unsigned*)&pz[(size_t)(l + j) * DINNER];
                ushort2 o;
                o.x = f2bf((y0 + Dd0 * xv0) * bflo(zp));
                o.y = f2bf((y1 + Dd1 * xv1) * bfhi(zp));
                *(ushort2*)&py[(size_t)(l + j) * DINNER] = o;
            }
        }
    };

    ldC(ga, pd, px, pbc, 0);
    for (int l0 = 0; l0 < CHLEN; l0 += 8) {
        ldC(gb, pd, px, pbc, l0 + 4);
        stepC(ga, l0);
        if (l0 + 8 < CHLEN) ldC(ga, pd, px, pbc, l0 + 8);
        stepC(gb, l0 + 4);
    }
}

__global__ void guard_kernel(float* out, int code)
{
    if (threadIdx.x == 0 && blockIdx.x == 0 && code) out[0] = (float)code;
}

extern "C" void kernel_launch(void* const* d_in, const int* in_sizes, int n_in,
                              void* d_out, int out_size, void* d_ws, size_t ws_size,
                              hipStream_t stream) {
    static const int EXPECTED[10] = {3145728, 2359296, 4608, 1536, 49152,
                                     2359296, 1536, 24576, 1536, 1179648};
    bool ok = (n_in == 10);
    if (ok) for (int i = 0; i < 10; ++i) ok = ok && (in_sizes[i] == EXPECTED[i]);
    int code = 0;
    if (!ok) code = 2000;
    else if (ws_size < 67895296ULL) code = 3000;
    if (code) { guard_kernel<<<1, 64, 0, stream>>>((float*)d_out, code); return; }

    const void* x       = d_in[0];
    const void* in_w    = d_in[1];
    const void* conv_w  = d_in[2];
    const void* conv_b  = d_in[3];
    const void* xproj_w = d_in[4];
    const void* dt_w    = d_in[5];
    const void* dt_b    = d_in[6];
    const void* A_log   = d_in[7];
    const void* Dvec    = d_in[8];
    const void* out_w   = d_in[9];

    char* ws = (char*)d_ws;
    float* conv_w_f = (float*)(ws + 0);        // 3 planes x 1536 f32 (18432 B)
    float* conv_b_f = (float*)(ws + 18432);    // 1536
    float* dt_b_f   = (float*)(ws + 24576);    // 1536
    float* A_log_f  = (float*)(ws + 30720);    // 24576 (holds A2 = -exp(A_log)*log2e)
    float* D_f      = (float*)(ws + 129024);   // 1536
    float* xproj_f  = (float*)(ws + 135168);   // 49152
    unsigned short* xb    = (unsigned short*)(ws + 524288);    // [4096][768]  (dead after gemm1)
    unsigned short* inT   = (unsigned short*)(ws + 6815744);   // [3072][768]  (dead after gemm1)
    unsigned short* yg    = (unsigned short*)(ws + 524288);    // [4096][1536] alias xb+inT
    unsigned short* dtT   = (unsigned short*)(ws + 13107200);  // [1536][1536]
    unsigned short* outT  = (unsigned short*)(ws + 17825792);  // [768][1536]
    unsigned short* xcpre = (unsigned short*)(ws + 20185088);  // [4096][1536] (dead after conv)
    unsigned short* dlt   = xcpre;                             // alias (gemm2 out)
    float*          BC    = (float*)(ws + 32768000);           // [4096][32]
    unsigned short* zg    = (unsigned short*)(ws + 33292288);  // [4096][1536] silu(z)
    unsigned short* xcb   = (unsigned short*)(ws + 45875200);  // [4096][1536]
    float*          scanS = (float*)(ws + 58458112);           // [2][32][1536][16] f32 6.29MB
    unsigned short* scanP = (unsigned short*)(ws + 64749568);  // same shape bf16   3.15MB

    prep_kernel<<<3300, 256, 0, stream>>>(x, in_w, conv_w, conv_b, xproj_w, dt_w,
                                          dt_b, A_log, Dvec, out_w,
                                          xb, inT, dtT, outT, (float*)ws);

    gemm_kernel<3><<<dim3(32, 48), 256, 0, stream>>>(xb, inT, (void*)xcpre, (void*)zg,
                                                     nullptr, 4096, 3072, 768);
    conv_silu_kernel<<<(4096 * DINNER / 8) / 256, 256, 0, stream>>>(xcpre, conv_w_f, conv_b_f, xcb);
    xproj_kernel<<<1024, 128, 0, stream>>>(xcb, xproj_f, BC);
    gemm_kernel<1><<<dim3(32, 24), 256, 0, stream>>>(xcb, dtT, (void*)dlt, nullptr,
                                                     dt_b_f, 4096, 1536, 1536);
    scan_phase_a<<<768, 256, 0, stream>>>(dlt, xcb, BC, A_log_f, scanP, scanS);
    scan_combine<<<192, 256, 0, stream>>>(scanP, scanS);
    scan_phase_c<<<768, 256, 0, stream>>>(dlt, xcb, BC, zg, A_log_f, D_f, scanS, yg);
    gemm_kernel<2><<<dim3(32, 12), 256, 0, stream>>>(yg, outT, d_out, nullptr,
                                                    nullptr, 4096, 768, 1536);
}